// Round 7
// baseline (228.566 us; speedup 1.0000x reference)
//
#include <hip/hip_runtime.h>
#include <hip/hip_bf16.h>
#include <math.h>

#define D_MODEL 1024
#define NHEADS  16
#define DK      64
#define SEQ     2048
#define BATCH   2
#define QTILE   64

typedef __attribute__((ext_vector_type(8))) short  short8;
typedef __attribute__((ext_vector_type(8))) unsigned short ushort8;
typedef __attribute__((ext_vector_type(4))) float  floatx4;

__device__ __forceinline__ unsigned short f2bf(float f) {      // RNE
    union { float f; unsigned int u; } v; v.f = f;
    unsigned int u = v.u;
    return (unsigned short)((u + 0x7FFFu + ((u >> 16) & 1u)) >> 16);
}
__device__ __forceinline__ float bf2f(unsigned short u) {
    union { unsigned int u; float f; } v; v.u = ((unsigned int)u) << 16;
    return v.f;
}
// pack two floats -> packed bf16 pair (round-half-up; softmax ratio cancels bias)
__device__ __forceinline__ unsigned int pack2bf(float a, float b) {
    union { float f; unsigned int u; } x, y; x.f = a; y.f = b;
    return ((x.u + 0x8000u) >> 16) | ((y.u + 0x8000u) & 0xFFFF0000u);
}

// async global->LDS, 16B per lane. LDS dest = wave-uniform base + lane*16.
__device__ __forceinline__ void gload_lds16(const unsigned short* g, unsigned short* l) {
    __builtin_amdgcn_global_load_lds((__attribute__((address_space(1))) const void*)g,
                                     (__attribute__((address_space(3))) void*)l,
                                     16, 0, 0);
}

// ---------------- fused fp32 -> bf16 pack of x, w_qkv, w_out ----------------
#define X8 ((BATCH * SEQ * D_MODEL) / 8)
#define W8 ((3 * D_MODEL * D_MODEL) / 8)
#define O8 ((D_MODEL * D_MODEL) / 8)
__global__ __launch_bounds__(256) void pack_all(const float* __restrict__ x,
                                                const float* __restrict__ wq,
                                                const float* __restrict__ wo,
                                                unsigned short* __restrict__ xb,
                                                unsigned short* __restrict__ wqb,
                                                unsigned short* __restrict__ wob) {
    const int t = blockIdx.x * blockDim.x + threadIdx.x;
    const float* src; unsigned short* dst; int idx;
    if (t < X8)           { src = x;  dst = xb;  idx = t; }
    else if (t < X8 + W8) { src = wq; dst = wqb; idx = t - X8; }
    else if (t < X8 + W8 + O8) { src = wo; dst = wob; idx = t - X8 - W8; }
    else return;
    const float4 a = ((const float4*)src)[2 * idx];
    const float4 b = ((const float4*)src)[2 * idx + 1];
    short8 o;
    o[0] = (short)f2bf(a.x); o[1] = (short)f2bf(a.y);
    o[2] = (short)f2bf(a.z); o[3] = (short)f2bf(a.w);
    o[4] = (short)f2bf(b.x); o[5] = (short)f2bf(b.y);
    o[6] = (short)f2bf(b.z); o[7] = (short)f2bf(b.w);
    ((short8*)dst)[idx] = o;
}

// ---------------- bf16 MFMA GEMM (m97 structure): C = A @ B^T (+bias) ----------------
template <int TM, typename OUT_T>
__global__ __launch_bounds__(256) void gemm_bf16(const unsigned short* __restrict__ A,
                                                 const unsigned short* __restrict__ B,
                                                 const float* __restrict__ bias,
                                                 OUT_T* __restrict__ C,
                                                 int M, int N, int K) {
    constexpr int NAF = TM / 32;               // A-frags per wave
    __shared__ __align__(16) unsigned short As[TM][32];
    __shared__ __align__(16) unsigned short Bs[128][32];

    const int tid  = threadIdx.x;
    const int wave = tid >> 6;
    const int lane = tid & 63;
    const int quad = lane >> 4;
    const int lcol = lane & 15;
    const int wr   = (wave >> 1) * (TM / 2);
    const int wc   = (wave & 1) * 64;
    const int tm   = blockIdx.y * TM;
    const int tn   = blockIdx.x * 128;

    const int srowA = wave * (TM / 4) + (lane >> 2);
    const int srowB = wave * 32 + (lane >> 2);
    const int scol  = (lane & 3) * 8;
    const unsigned short* gB0 = B + (size_t)(tn + srowB) * K + scol;
    const unsigned short* gB1 = gB0 + (size_t)16 * K;
    unsigned short* lB0 = &Bs[wave * 32][0];
    unsigned short* lB1 = &Bs[wave * 32 + 16][0];

    floatx4 acc[NAF][4];
#pragma unroll
    for (int i = 0; i < NAF; ++i)
#pragma unroll
        for (int j = 0; j < 4; ++j) acc[i][j] = (floatx4){0.f, 0.f, 0.f, 0.f};

    for (int k0 = 0; k0 < K; k0 += 32) {
        __syncthreads();
#pragma unroll
        for (int u = 0; u < TM / 64; ++u)
            gload_lds16(A + (size_t)(tm + srowA + u * 16) * K + k0 + scol,
                        &As[wave * (TM / 4) + u * 16][0]);
        gload_lds16(gB0 + k0, lB0);
        gload_lds16(gB1 + k0, lB1);
        __syncthreads();

        short8 af[NAF], bf[4];
#pragma unroll
        for (int i = 0; i < NAF; ++i) af[i] = *(short8*)&As[wr + i * 16 + lcol][quad * 8];
#pragma unroll
        for (int j = 0; j < 4; ++j) bf[j] = *(short8*)&Bs[wc + j * 16 + lcol][quad * 8];
#pragma unroll
        for (int i = 0; i < NAF; ++i)
#pragma unroll
            for (int j = 0; j < 4; ++j)
                acc[i][j] = __builtin_amdgcn_mfma_f32_16x16x32_bf16(af[i], bf[j], acc[i][j], 0, 0, 0);
    }

#pragma unroll
    for (int i = 0; i < NAF; ++i) {
#pragma unroll
        for (int r = 0; r < 4; ++r) {
            const int row = tm + wr + i * 16 + quad * 4 + r;
#pragma unroll
            for (int j = 0; j < 4; ++j) {
                const int col = tn + wc + j * 16 + lcol;
                float v = acc[i][j][r];
                if (bias) v += bias[col];
                if constexpr (sizeof(OUT_T) == 2)
                    C[(size_t)row * N + col] = (OUT_T)f2bf(v);
                else
                    C[(size_t)row * N + col] = (OUT_T)v;
            }
        }
    }
}

// ---------------- fused RoPE pack (Q*0.125*log2e, K) + half-kappa V transpose ------
// Within each 64-key tile, keys are stored per 32-half: column = half*32 + (u&15)*2 + (u>>4)
// where u = key index within the half. flash contracts P and V in this same order.
__global__ __launch_bounds__(256) void rope_vtrans(const unsigned short* __restrict__ qkvb,
                                                   unsigned short* __restrict__ Qb,
                                                   unsigned short* __restrict__ Kb,
                                                   unsigned short* __restrict__ Vtg) {
    const int st = blockIdx.x, h = blockIdx.y, b = blockIdx.z;
    const int tid = threadIdx.x;
    const int s0 = st * 64;

    // ---- RoPE on Q,K ----
    const int i  = tid & 31;
    const int r0 = tid >> 5;                   // 0..7
    const float inv_freq = exp2f(-(2.0f * (float)i / (float)DK) * log2f(50.0f));
    const float QSCALE = 0.125f * 1.44269504f; // 1/sqrt(dk) * log2(e)
#pragma unroll
    for (int pass = 0; pass < 8; ++pass) {
        const int s = s0 + r0 + pass * 8;
        const size_t in_base = ((size_t)(b * SEQ + s)) * (3 * D_MODEL) + h * DK + 2 * i;
        const float q0 = bf2f(qkvb[in_base]),           q1 = bf2f(qkvb[in_base + 1]);
        const float k0 = bf2f(qkvb[in_base + D_MODEL]), k1 = bf2f(qkvb[in_base + D_MODEL + 1]);
        float sn, cs;
        __sincosf((float)s * inv_freq, &sn, &cs);
        const size_t ob = (((size_t)(b * NHEADS + h)) * SEQ + s) * DK + 2 * i;
        const unsigned int qw = (unsigned int)f2bf((q0 * cs - q1 * sn) * QSCALE)
                              | ((unsigned int)f2bf((q1 * cs + q0 * sn) * QSCALE) << 16);
        const unsigned int kw = (unsigned int)f2bf(k0 * cs - k1 * sn)
                              | ((unsigned int)f2bf(k1 * cs + k0 * sn) << 16);
        *(unsigned int*)&Qb[ob] = qw;
        *(unsigned int*)&Kb[ob] = kw;
    }

    // ---- V transpose with per-32-half kappa permutation ----
    __shared__ unsigned short Lt[64][65];
    const int r = tid >> 3;                    // 0..31 (key row within tile-half)
    const int c = (tid & 7) * 8;
    const size_t in_row = ((size_t)(b * SEQ + s0 + r)) * (3 * D_MODEL) + 2 * D_MODEL + h * DK + c;
    const ushort8 v0 = *(const ushort8*)&qkvb[in_row];
    const ushort8 v1 = *(const ushort8*)&qkvb[in_row + (size_t)32 * (3 * D_MODEL)];
    const int kr0 = (r & 15) * 2 + (r >> 4);          // key r      -> half 0
    const int kr1 = 32 + (r & 15) * 2 + (r >> 4);     // key r + 32 -> half 1
#pragma unroll
    for (int j = 0; j < 8; ++j) Lt[c + j][kr0] = v0[j];
#pragma unroll
    for (int j = 0; j < 8; ++j) Lt[c + j][kr1] = v1[j];
    __syncthreads();
    const size_t bh = (size_t)(b * NHEADS + h);
    ushort8 o0, o1;
#pragma unroll
    for (int j = 0; j < 8; ++j) { o0[j] = Lt[r][c + j]; o1[j] = Lt[r + 32][c + j]; }
    unsigned short* orow = Vtg + (bh * DK + r) * SEQ + s0 + c;   // here r = d-row
    *(ushort8*)orow = o0;
    *(ushort8*)(orow + (size_t)32 * SEQ) = o1;
}

// ---------------- flash attention: 2x2 wave split (m-half x key-half) --------------
#define LDW 72

__global__ __launch_bounds__(256) void flash_attn(const unsigned short* __restrict__ Qb,
                                                  const unsigned short* __restrict__ Kb,
                                                  const unsigned short* __restrict__ Vtg,
                                                  unsigned short* __restrict__ attnb) {
    const int qt   = blockIdx.x;              // 0..31 (tiles of 64 queries)
    const int h    = blockIdx.y;
    const int b    = blockIdx.z;
    const int tid  = threadIdx.x;
    const int wave = tid >> 6;
    const int lane = tid & 63;
    const int quad = lane >> 4;
    const int lcol = lane & 15;
    const int mh   = wave & 1;                // m-half
    const int kh   = wave >> 1;               // key-half
    const int m0   = mh * 32;
    const int kb   = kh * 32;

    __shared__ __align__(16) unsigned short smem[3 * 64 * LDW];   // 27648 B
    unsigned short (*Ks)[LDW] = (unsigned short (*)[LDW])smem;
    unsigned short (*Vt)[LDW] = (unsigned short (*)[LDW])(smem + 64 * LDW);
    unsigned short (*Ps)[LDW] = (unsigned short (*)[LDW])(smem + 2 * 64 * LDW);
    // post-loop overlays (Ks/Vt/Ps dead by then):
    float (*Ored)[68] = (float (*)[68])smem;                      // 64*68*4 = 17408 B
    float* lred = (float*)(smem + 2 * 64 * LDW);                  // 256 B

    const size_t bh = (size_t)(b * NHEADS + h);
    const unsigned short* Qg = Qb + (bh * SEQ + (size_t)qt * QTILE) * DK;
    const unsigned short* Kg = Kb + bh * SEQ * DK;
    const unsigned short* Vg = Vtg + bh * (size_t)DK * SEQ;

    // Q fragments: rows m0 + mf*16 + lcol (one-time)
    short8 qf[2][2];
#pragma unroll
    for (int mf = 0; mf < 2; ++mf)
#pragma unroll
        for (int hf = 0; hf < 2; ++hf)
            qf[mf][hf] = *(const short8*)&Qg[(size_t)(m0 + mf * 16 + lcol) * DK + hf * 32 + quad * 8];

    const int strow = tid >> 3;               // 0..31
    const int stcol = (tid & 7) * 8;
    const unsigned short* kg0 = &Kg[(size_t)strow * DK + stcol];
    const unsigned short* kg1 = &Kg[(size_t)(strow + 32) * DK + stcol];
    const unsigned short* vg0 = &Vg[(size_t)strow * SEQ + stcol];
    const unsigned short* vg1 = &Vg[(size_t)(strow + 32) * SEQ + stcol];

    short8 kr0 = *(const short8*)&kg0[0];
    short8 kr1 = *(const short8*)&kg1[0];
    short8 vr0 = *(const short8*)&vg0[0];
    short8 vr1 = *(const short8*)&vg1[0];

    floatx4 oacc[2][4];
    float lp[8];
#pragma unroll
    for (int mf = 0; mf < 2; ++mf)
#pragma unroll
        for (int n = 0; n < 4; ++n) oacc[mf][n] = (floatx4){0.f, 0.f, 0.f, 0.f};
#pragma unroll
    for (int r = 0; r < 8; ++r) lp[r] = 0.f;

    for (int kt = 0; kt < SEQ; kt += 64) {
        __syncthreads();
        *(short8*)&Ks[strow][stcol]      = kr0;
        *(short8*)&Ks[strow + 32][stcol] = kr1;
        *(short8*)&Vt[strow][stcol]      = vr0;
        *(short8*)&Vt[strow + 32][stcol] = vr1;
        __syncthreads();

        const int ktn = (kt + 64 < SEQ) ? kt + 64 : 0;
        kr0 = *(const short8*)&kg0[(size_t)ktn * DK];
        kr1 = *(const short8*)&kg1[(size_t)ktn * DK];
        vr0 = *(const short8*)&vg0[ktn];
        vr1 = *(const short8*)&vg1[ktn];

        // ---- S = Q K^T : this wave's 32m x 32keys (8 MFMAs, 4 K-frag reads) ----
        floatx4 s[2][2];
#pragma unroll
        for (int nf = 0; nf < 2; ++nf) {
            const short8 kf0 = *(short8*)&Ks[kb + nf * 16 + lcol][quad * 8];
            const short8 kf1 = *(short8*)&Ks[kb + nf * 16 + lcol][32 + quad * 8];
#pragma unroll
            for (int mf = 0; mf < 2; ++mf) {
                floatx4 a = (floatx4){0.f, 0.f, 0.f, 0.f};
                a = __builtin_amdgcn_mfma_f32_16x16x32_bf16(qf[mf][0], kf0, a, 0, 0, 0);
                a = __builtin_amdgcn_mfma_f32_16x16x32_bf16(qf[mf][1], kf1, a, 0, 0, 0);
                s[mf][nf] = a;
            }
        }

        // ---- diagonal mask: only the tile at kt==qt*64, only waves with kh==mh ----
        if (kt == qt * QTILE && kh == mh) {
#pragma unroll
            for (int mf = 0; mf < 2; ++mf)
#pragma unroll
                for (int nf = 0; nf < 2; ++nf) {
                    const int kl = nf * 16 + lcol;          // key within half
                    const int ql = mf * 16 + quad * 4;      // q within half (+r)
#pragma unroll
                    for (int r = 0; r < 4; ++r)
                        if (kl == ql + r) s[mf][nf][r] = -1e30f;
                }
        }

        // ---- P = exp2(S); partial row sums over this wave's keys; b32 kappa spill ----
#pragma unroll
        for (int mf = 0; mf < 2; ++mf)
#pragma unroll
            for (int r = 0; r < 4; ++r) {
                const float p0 = exp2f(s[mf][0][r]);
                const float p1 = exp2f(s[mf][1][r]);
                lp[mf * 4 + r] += p0 + p1;
                // kappa within half = lcol*2 + nf
                *(unsigned int*)&Ps[m0 + mf * 16 + quad * 4 + r][kb + lcol * 2] = pack2bf(p0, p1);
            }
        // Ps rows [m0, m0+32) cols [kb, kb+32) are wave-private -> no barrier

        // ---- O += P V over this wave's 32 keys (K=32: one MFMA per (mf, d-tile)) ----
        short8 pf[2];
#pragma unroll
        for (int mf = 0; mf < 2; ++mf)
            pf[mf] = *(short8*)&Ps[m0 + mf * 16 + lcol][kb + quad * 8];
#pragma unroll
        for (int n = 0; n < 4; ++n) {
            const short8 vf = *(short8*)&Vt[n * 16 + lcol][kb + quad * 8];
#pragma unroll
            for (int mf = 0; mf < 2; ++mf)
                oacc[mf][n] = __builtin_amdgcn_mfma_f32_16x16x32_bf16(pf[mf], vf, oacc[mf][n], 0, 0, 0);
        }
    }

    // ---- l: reduce across the 16 lanes sharing each row ----
#pragma unroll
    for (int r = 0; r < 8; ++r)
#pragma unroll
        for (int off = 1; off <= 8; off <<= 1)
            lp[r] += __shfl_xor(lp[r], off, 64);

    // ---- cross-wave (key-half) reduction through LDS overlay ----
    __syncthreads();                          // Ks/Vt/Ps dead; safe to overlay
    if (kh == 1) {
#pragma unroll
        for (int mf = 0; mf < 2; ++mf) {
#pragma unroll
            for (int r = 0; r < 4; ++r) {
                const int row = m0 + mf * 16 + quad * 4 + r;
                if (lcol == 0) lred[row] = lp[mf * 4 + r];
#pragma unroll
                for (int n = 0; n < 4; ++n)
                    Ored[row][n * 16 + lcol] = oacc[mf][n][r];
            }
        }
    }
    __syncthreads();
    if (kh == 0) {
        unsigned short* obase = attnb + ((size_t)b * SEQ + (size_t)qt * QTILE) * D_MODEL + h * DK;
#pragma unroll
        for (int mf = 0; mf < 2; ++mf) {
#pragma unroll
            for (int r = 0; r < 4; ++r) {
                const int row = m0 + mf * 16 + quad * 4 + r;
                const float inv = 1.0f / (lp[mf * 4 + r] + lred[row]);
#pragma unroll
                for (int n = 0; n < 4; ++n) {
                    const float v = (oacc[mf][n][r] + Ored[row][n * 16 + lcol]) * inv;
                    obase[(size_t)row * D_MODEL + n * 16 + lcol] = f2bf(v);
                }
            }
        }
    }
}

extern "C" void kernel_launch(void* const* d_in, const int* in_sizes, int n_in,
                              void* d_out, int out_size, void* d_ws, size_t ws_size,
                              hipStream_t stream) {
    const float* x     = (const float*)d_in[0];
    const float* w_qkv = (const float*)d_in[1];
    const float* w_out = (const float*)d_in[2];
    const float* b_out = (const float*)d_in[3];
    float* out = (float*)d_out;

    const int M = BATCH * SEQ;                                   // 4096
    const size_t X_ELEMS    = (size_t)M * D_MODEL;
    const size_t WQKV_ELEMS = (size_t)3 * D_MODEL * D_MODEL;
    const size_t WOUT_ELEMS = (size_t)D_MODEL * D_MODEL;
    const size_t QKV_ELEMS  = (size_t)M * 3 * D_MODEL;
    const size_t HEAD_ELEMS = (size_t)BATCH * NHEADS * SEQ * DK;

    unsigned short* xb    = (unsigned short*)d_ws;
    unsigned short* wqkvb = xb + X_ELEMS;
    unsigned short* woutb = wqkvb + WQKV_ELEMS;
    unsigned short* qkvb  = woutb + WOUT_ELEMS;
    unsigned short* Qb    = qkvb + QKV_ELEMS;
    unsigned short* Kb    = Qb + HEAD_ELEMS;
    unsigned short* Vtg   = Kb + HEAD_ELEMS;                     // [B,H,64,S] (half-kappa cols)
    unsigned short* attnb = Vtg + HEAD_ELEMS;

    // 0) pack all inputs to bf16
    pack_all<<<(X8 + W8 + O8 + 255) / 256, 256, 0, stream>>>(x, w_qkv, w_out, xb, wqkvb, woutb);

    // 1) qkvb = xb @ wqkvb^T
    {
        dim3 grid(3 * D_MODEL / 128, M / 128);
        gemm_bf16<128, unsigned short><<<grid, 256, 0, stream>>>(xb, wqkvb, nullptr, qkvb,
                                                                 M, 3 * D_MODEL, D_MODEL);
    }
    // 2) RoPE pack + half-kappa V transpose
    {
        dim3 grid(SEQ / 64, NHEADS, BATCH);
        rope_vtrans<<<grid, 256, 0, stream>>>(qkvb, Qb, Kb, Vtg);
    }
    // 3) flash attention (2x2 wave split)
    {
        dim3 grid(SEQ / QTILE, NHEADS, BATCH);
        flash_attn<<<grid, 256, 0, stream>>>(Qb, Kb, Vtg, attnb);
    }
    // 4) out = attnb @ woutb^T + b_out  (64x128 tiles -> 512 blocks, 2/CU)
    {
        dim3 grid(D_MODEL / 128, M / 64);
        gemm_bf16<64, float><<<grid, 256, 0, stream>>>(attnb, woutb, b_out, out,
                                                       M, D_MODEL, D_MODEL);
    }
}

// Round 8
// 224.505 us; speedup vs baseline: 1.0181x; 1.0181x over previous
//
#include <hip/hip_runtime.h>
#include <hip/hip_bf16.h>
#include <math.h>

#define D_MODEL 1024
#define NHEADS  16
#define DK      64
#define SEQ     2048
#define BATCH   2
#define QTILE   64

typedef __attribute__((ext_vector_type(8))) short  short8;
typedef __attribute__((ext_vector_type(8))) unsigned short ushort8;
typedef __attribute__((ext_vector_type(4))) float  floatx4;

__device__ __forceinline__ unsigned short f2bf(float f) {      // RNE
    union { float f; unsigned int u; } v; v.f = f;
    unsigned int u = v.u;
    return (unsigned short)((u + 0x7FFFu + ((u >> 16) & 1u)) >> 16);
}
__device__ __forceinline__ unsigned short f2bf_trunc(float f) { // truncate (0 extra VALU w/ d16_hi)
    union { float f; unsigned int u; } v; v.f = f;
    return (unsigned short)(v.u >> 16);
}
__device__ __forceinline__ float bf2f(unsigned short u) {
    union { unsigned int u; float f; } v; v.u = ((unsigned int)u) << 16;
    return v.f;
}

// async global->LDS, 16B per lane. LDS dest = wave-uniform base + lane*16.
__device__ __forceinline__ void gload_lds16(const unsigned short* g, unsigned short* l) {
    __builtin_amdgcn_global_load_lds((__attribute__((address_space(1))) const void*)g,
                                     (__attribute__((address_space(3))) void*)l,
                                     16, 0, 0);
}

// ---------------- fused fp32 -> bf16 pack of x, w_qkv, w_out ----------------
#define X8 ((BATCH * SEQ * D_MODEL) / 8)
#define W8 ((3 * D_MODEL * D_MODEL) / 8)
#define O8 ((D_MODEL * D_MODEL) / 8)
__global__ __launch_bounds__(256) void pack_all(const float* __restrict__ x,
                                                const float* __restrict__ wq,
                                                const float* __restrict__ wo,
                                                unsigned short* __restrict__ xb,
                                                unsigned short* __restrict__ wqb,
                                                unsigned short* __restrict__ wob) {
    const int t = blockIdx.x * blockDim.x + threadIdx.x;
    const float* src; unsigned short* dst; int idx;
    if (t < X8)           { src = x;  dst = xb;  idx = t; }
    else if (t < X8 + W8) { src = wq; dst = wqb; idx = t - X8; }
    else if (t < X8 + W8 + O8) { src = wo; dst = wob; idx = t - X8 - W8; }
    else return;
    const float4 a = ((const float4*)src)[2 * idx];
    const float4 b = ((const float4*)src)[2 * idx + 1];
    short8 o;
    o[0] = (short)f2bf(a.x); o[1] = (short)f2bf(a.y);
    o[2] = (short)f2bf(a.z); o[3] = (short)f2bf(a.w);
    o[4] = (short)f2bf(b.x); o[5] = (short)f2bf(b.y);
    o[6] = (short)f2bf(b.z); o[7] = (short)f2bf(b.w);
    ((short8*)dst)[idx] = o;
}

// ---------------- bf16 MFMA GEMM (m97 structure): C = A @ B^T (+bias) ----------------
template <int TM, typename OUT_T>
__global__ __launch_bounds__(256) void gemm_bf16(const unsigned short* __restrict__ A,
                                                 const unsigned short* __restrict__ B,
                                                 const float* __restrict__ bias,
                                                 OUT_T* __restrict__ C,
                                                 int M, int N, int K) {
    constexpr int NAF = TM / 32;               // A-frags per wave
    __shared__ __align__(16) unsigned short As[TM][32];
    __shared__ __align__(16) unsigned short Bs[128][32];

    const int tid  = threadIdx.x;
    const int wave = tid >> 6;
    const int lane = tid & 63;
    const int quad = lane >> 4;
    const int lcol = lane & 15;
    const int wr   = (wave >> 1) * (TM / 2);
    const int wc   = (wave & 1) * 64;
    const int tm   = blockIdx.y * TM;
    const int tn   = blockIdx.x * 128;

    const int srowA = wave * (TM / 4) + (lane >> 2);
    const int srowB = wave * 32 + (lane >> 2);
    const int scol  = (lane & 3) * 8;
    const unsigned short* gB0 = B + (size_t)(tn + srowB) * K + scol;
    const unsigned short* gB1 = gB0 + (size_t)16 * K;
    unsigned short* lB0 = &Bs[wave * 32][0];
    unsigned short* lB1 = &Bs[wave * 32 + 16][0];

    floatx4 acc[NAF][4];
#pragma unroll
    for (int i = 0; i < NAF; ++i)
#pragma unroll
        for (int j = 0; j < 4; ++j) acc[i][j] = (floatx4){0.f, 0.f, 0.f, 0.f};

    for (int k0 = 0; k0 < K; k0 += 32) {
        __syncthreads();
#pragma unroll
        for (int u = 0; u < TM / 64; ++u)
            gload_lds16(A + (size_t)(tm + srowA + u * 16) * K + k0 + scol,
                        &As[wave * (TM / 4) + u * 16][0]);
        gload_lds16(gB0 + k0, lB0);
        gload_lds16(gB1 + k0, lB1);
        __syncthreads();

        short8 af[NAF], bf[4];
#pragma unroll
        for (int i = 0; i < NAF; ++i) af[i] = *(short8*)&As[wr + i * 16 + lcol][quad * 8];
#pragma unroll
        for (int j = 0; j < 4; ++j) bf[j] = *(short8*)&Bs[wc + j * 16 + lcol][quad * 8];
#pragma unroll
        for (int i = 0; i < NAF; ++i)
#pragma unroll
            for (int j = 0; j < 4; ++j)
                acc[i][j] = __builtin_amdgcn_mfma_f32_16x16x32_bf16(af[i], bf[j], acc[i][j], 0, 0, 0);
    }

#pragma unroll
    for (int i = 0; i < NAF; ++i) {
#pragma unroll
        for (int r = 0; r < 4; ++r) {
            const int row = tm + wr + i * 16 + quad * 4 + r;
#pragma unroll
            for (int j = 0; j < 4; ++j) {
                const int col = tn + wc + j * 16 + lcol;
                float v = acc[i][j][r];
                if (bias) v += bias[col];
                if constexpr (sizeof(OUT_T) == 2)
                    C[(size_t)row * N + col] = (OUT_T)f2bf(v);
                else
                    C[(size_t)row * N + col] = (OUT_T)v;
            }
        }
    }
}

// ---------------- fused RoPE pack (Q*0.125*log2e, K) + V transpose ----------------
__global__ __launch_bounds__(256) void rope_vtrans(const unsigned short* __restrict__ qkvb,
                                                   unsigned short* __restrict__ Qb,
                                                   unsigned short* __restrict__ Kb,
                                                   unsigned short* __restrict__ Vtg) {
    const int st = blockIdx.x, h = blockIdx.y, b = blockIdx.z;
    const int tid = threadIdx.x;
    const int s0 = st * 64;

    // ---- RoPE on Q,K ----
    const int i  = tid & 31;
    const int r0 = tid >> 5;                   // 0..7
    const float inv_freq = exp2f(-(2.0f * (float)i / (float)DK) * log2f(50.0f));
    const float QSCALE = 0.125f * 1.44269504f; // 1/sqrt(dk) * log2(e)
#pragma unroll
    for (int pass = 0; pass < 8; ++pass) {
        const int s = s0 + r0 + pass * 8;
        const size_t in_base = ((size_t)(b * SEQ + s)) * (3 * D_MODEL) + h * DK + 2 * i;
        const float q0 = bf2f(qkvb[in_base]),           q1 = bf2f(qkvb[in_base + 1]);
        const float k0 = bf2f(qkvb[in_base + D_MODEL]), k1 = bf2f(qkvb[in_base + D_MODEL + 1]);
        float sn, cs;
        __sincosf((float)s * inv_freq, &sn, &cs);
        const size_t ob = (((size_t)(b * NHEADS + h)) * SEQ + s) * DK + 2 * i;
        const unsigned int qw = (unsigned int)f2bf((q0 * cs - q1 * sn) * QSCALE)
                              | ((unsigned int)f2bf((q1 * cs + q0 * sn) * QSCALE) << 16);
        const unsigned int kw = (unsigned int)f2bf(k0 * cs - k1 * sn)
                              | ((unsigned int)f2bf(k1 * cs + k0 * sn) << 16);
        *(unsigned int*)&Qb[ob] = qw;
        *(unsigned int*)&Kb[ob] = kw;
    }

    // ---- V transpose ----
    __shared__ unsigned short Lt[64][65];
    const int r = tid >> 3;                    // 0..31
    const int c = (tid & 7) * 8;
    const size_t in_row = ((size_t)(b * SEQ + s0 + r)) * (3 * D_MODEL) + 2 * D_MODEL + h * DK + c;
    const ushort8 v0 = *(const ushort8*)&qkvb[in_row];
    const ushort8 v1 = *(const ushort8*)&qkvb[in_row + (size_t)32 * (3 * D_MODEL)];
#pragma unroll
    for (int j = 0; j < 8; ++j) Lt[c + j][r]      = v0[j];
#pragma unroll
    for (int j = 0; j < 8; ++j) Lt[c + j][r + 32] = v1[j];
    __syncthreads();
    const size_t bh = (size_t)(b * NHEADS + h);
    ushort8 o0, o1;
#pragma unroll
    for (int j = 0; j < 8; ++j) { o0[j] = Lt[r][c + j]; o1[j] = Lt[r + 32][c + j]; }
    unsigned short* orow = Vtg + (bh * DK + r) * SEQ + s0 + c;   // r = d-row
    *(ushort8*)orow = o0;
    *(ushort8*)(orow + (size_t)32 * SEQ) = o1;
}

// ---------------- flash attention: 64-q tile, deferred softmax, l via ones-MFMA ----
#define LDW 72

__global__ __launch_bounds__(256) void flash_attn(const unsigned short* __restrict__ Qb,
                                                  const unsigned short* __restrict__ Kb,
                                                  const unsigned short* __restrict__ Vtg,
                                                  unsigned short* __restrict__ attnb) {
    const int qt   = blockIdx.x;              // 0..31 (tiles of 64 queries)
    const int h    = blockIdx.y;
    const int b    = blockIdx.z;
    const int tid  = threadIdx.x;
    const int wave = tid >> 6;
    const int lane = tid & 63;
    const int quad = lane >> 4;
    const int lcol = lane & 15;
    const int m0   = wave * 16;

    __shared__ __align__(16) unsigned short Ks[64][LDW];
    __shared__ __align__(16) unsigned short Vt[64][LDW];    // [d][key]
    __shared__ __align__(16) unsigned short Ps[QTILE][LDW]; // [m][key]

    const size_t bh = (size_t)(b * NHEADS + h);
    const unsigned short* Qg = Qb + (bh * SEQ + (size_t)qt * QTILE) * DK;
    const unsigned short* Kg = Kb + bh * SEQ * DK;
    const unsigned short* Vg = Vtg + bh * (size_t)DK * SEQ;

    // Q fragments (one-time, from global)
    const unsigned short* qrow = Qg + (size_t)(m0 + lcol) * DK;
    const short8 qf0 = *(const short8*)&qrow[quad * 8];
    const short8 qf1 = *(const short8*)&qrow[32 + quad * 8];

    // constant bf16 1.0 B-fragment for the l (row-sum) MFMA
    short8 ones;
#pragma unroll
    for (int j = 0; j < 8; ++j) ones[j] = (short)0x3F80;

    const int strow = tid >> 3;               // 0..31
    const int stcol = (tid & 7) * 8;
    const unsigned short* kg0 = &Kg[(size_t)strow * DK + stcol];
    const unsigned short* kg1 = &Kg[(size_t)(strow + 32) * DK + stcol];
    const unsigned short* vg0 = &Vg[(size_t)strow * SEQ + stcol];
    const unsigned short* vg1 = &Vg[(size_t)(strow + 32) * SEQ + stcol];

    short8 kr0 = *(const short8*)&kg0[0];
    short8 kr1 = *(const short8*)&kg1[0];
    short8 vr0 = *(const short8*)&vg0[0];
    short8 vr1 = *(const short8*)&vg1[0];

    floatx4 oacc[4];
    floatx4 lacc = (floatx4){0.f, 0.f, 0.f, 0.f};
#pragma unroll
    for (int n = 0; n < 4; ++n) oacc[n] = (floatx4){0.f, 0.f, 0.f, 0.f};

    const int diag_kt = qt * QTILE;           // tile containing this block's diagonal
    const int q_glob0 = qt * QTILE + m0 + quad * 4;

    for (int kt = 0; kt < SEQ; kt += 64) {
        __syncthreads();
        *(short8*)&Ks[strow][stcol]      = kr0;
        *(short8*)&Ks[strow + 32][stcol] = kr1;
        *(short8*)&Vt[strow][stcol]      = vr0;
        *(short8*)&Vt[strow + 32][stcol] = vr1;
        __syncthreads();

        const int ktn = (kt + 64 < SEQ) ? kt + 64 : 0;
        kr0 = *(const short8*)&kg0[(size_t)ktn * DK];
        kr1 = *(const short8*)&kg1[(size_t)ktn * DK];
        vr0 = *(const short8*)&vg0[ktn];
        vr1 = *(const short8*)&vg1[ktn];

        // ---- S = Q K^T ----
        floatx4 s[4];
#pragma unroll
        for (int n = 0; n < 4; ++n) {
            const short8 kf0 = *(short8*)&Ks[n * 16 + lcol][quad * 8];
            const short8 kf1 = *(short8*)&Ks[n * 16 + lcol][32 + quad * 8];
            floatx4 a = (floatx4){0.f, 0.f, 0.f, 0.f};
            a = __builtin_amdgcn_mfma_f32_16x16x32_bf16(qf0, kf0, a, 0, 0, 0);
            a = __builtin_amdgcn_mfma_f32_16x16x32_bf16(qf1, kf1, a, 0, 0, 0);
            s[n] = a;
        }

        // ---- diagonal mask (wave-uniform branch; 1 of 32 tiles) ----
        if (kt == diag_kt) {
#pragma unroll
            for (int n = 0; n < 4; ++n) {
                const int kg = kt + n * 16 + lcol;
#pragma unroll
                for (int r = 0; r < 4; ++r)
                    if (kg == q_glob0 + r) s[n][r] = -1e30f;
            }
        }

        // ---- P = exp2(S) (log2e folded into Q); truncation spill (no rounding ops) ----
#pragma unroll
        for (int n = 0; n < 4; ++n)
#pragma unroll
            for (int r = 0; r < 4; ++r)
                Ps[m0 + quad * 4 + r][n * 16 + lcol] = f2bf_trunc(exp2f(s[n][r]));
        // Ps rows [m0, m0+16) are wave-private -> no barrier

        // ---- P fragments ----
        const short8 pf0 = *(short8*)&Ps[m0 + lcol][quad * 8];
        const short8 pf1 = *(short8*)&Ps[m0 + lcol][32 + quad * 8];

        // ---- l += P @ ones  (row sums of the SAME quantized P, on the matrix pipe) ----
        lacc = __builtin_amdgcn_mfma_f32_16x16x32_bf16(pf0, ones, lacc, 0, 0, 0);
        lacc = __builtin_amdgcn_mfma_f32_16x16x32_bf16(pf1, ones, lacc, 0, 0, 0);

        // ---- O += P V ----
#pragma unroll
        for (int n = 0; n < 4; ++n) {
            const short8 vf0 = *(short8*)&Vt[n * 16 + lcol][quad * 8];
            const short8 vf1 = *(short8*)&Vt[n * 16 + lcol][32 + quad * 8];
            oacc[n] = __builtin_amdgcn_mfma_f32_16x16x32_bf16(pf0, vf0, oacc[n], 0, 0, 0);
            oacc[n] = __builtin_amdgcn_mfma_f32_16x16x32_bf16(pf1, vf1, oacc[n], 0, 0, 0);
        }
    }

    // ---- epilogue: lacc[r] holds the full row sum (replicated across cols) ----
    unsigned short* obase = attnb + ((size_t)b * SEQ + (size_t)qt * QTILE) * D_MODEL + h * DK;
#pragma unroll
    for (int r = 0; r < 4; ++r) {
        const float inv = 1.0f / lacc[r];
        const int qrow2 = m0 + quad * 4 + r;
#pragma unroll
        for (int n = 0; n < 4; ++n)
            obase[(size_t)qrow2 * D_MODEL + n * 16 + lcol] = f2bf(oacc[n][r] * inv);
    }
}

extern "C" void kernel_launch(void* const* d_in, const int* in_sizes, int n_in,
                              void* d_out, int out_size, void* d_ws, size_t ws_size,
                              hipStream_t stream) {
    const float* x     = (const float*)d_in[0];
    const float* w_qkv = (const float*)d_in[1];
    const float* w_out = (const float*)d_in[2];
    const float* b_out = (const float*)d_in[3];
    float* out = (float*)d_out;

    const int M = BATCH * SEQ;                                   // 4096
    const size_t X_ELEMS    = (size_t)M * D_MODEL;
    const size_t WQKV_ELEMS = (size_t)3 * D_MODEL * D_MODEL;
    const size_t WOUT_ELEMS = (size_t)D_MODEL * D_MODEL;
    const size_t QKV_ELEMS  = (size_t)M * 3 * D_MODEL;
    const size_t HEAD_ELEMS = (size_t)BATCH * NHEADS * SEQ * DK;

    unsigned short* xb    = (unsigned short*)d_ws;
    unsigned short* wqkvb = xb + X_ELEMS;
    unsigned short* woutb = wqkvb + WQKV_ELEMS;
    unsigned short* qkvb  = woutb + WOUT_ELEMS;
    unsigned short* Qb    = qkvb + QKV_ELEMS;
    unsigned short* Kb    = Qb + HEAD_ELEMS;
    unsigned short* Vtg   = Kb + HEAD_ELEMS;                     // [B,H,64,S]
    unsigned short* attnb = Vtg + HEAD_ELEMS;

    // 0) pack all inputs to bf16
    pack_all<<<(X8 + W8 + O8 + 255) / 256, 256, 0, stream>>>(x, w_qkv, w_out, xb, wqkvb, woutb);

    // 1) qkvb = xb @ wqkvb^T
    {
        dim3 grid(3 * D_MODEL / 128, M / 128);
        gemm_bf16<128, unsigned short><<<grid, 256, 0, stream>>>(xb, wqkvb, nullptr, qkvb,
                                                                 M, 3 * D_MODEL, D_MODEL);
    }
    // 2) RoPE pack + V transpose
    {
        dim3 grid(SEQ / 64, NHEADS, BATCH);
        rope_vtrans<<<grid, 256, 0, stream>>>(qkvb, Qb, Kb, Vtg);
    }
    // 3) flash attention
    {
        dim3 grid(SEQ / QTILE, NHEADS, BATCH);
        flash_attn<<<grid, 256, 0, stream>>>(Qb, Kb, Vtg, attnb);
    }
    // 4) out = attnb @ woutb^T + b_out  (64x128 tiles -> 512 blocks, 2/CU)
    {
        dim3 grid(D_MODEL / 128, M / 64);
        gemm_bf16<64, float><<<grid, 256, 0, stream>>>(attnb, woutb, b_out, out,
                                                       M, D_MODEL, D_MODEL);
    }
}